// Round 7
// baseline (248.354 us; speedup 1.0000x reference)
//
#include <hip/hip_runtime.h>
#include <stdint.h>

#define NEGF   (-1.0e30f)
#define LOG2E  1.4426950408889634f
#define LN2    0.6931471805599453f

// lane i <- lane i-1 (wave_shr:1 = 0x138), lane 0 <- NEGF (old value, bound_ctrl=false)
__device__ __forceinline__ float dpp_shr1(float x) {
  int r = __builtin_amdgcn_update_dpp(__float_as_int(NEGF), __float_as_int(x),
                                      0x138, 0xf, 0xf, false);
  return __int_as_float(r);
}

__device__ __forceinline__ float ladd2(float a, float b) {
  float m = fmaxf(a, b);
  float n = fminf(a, b);
  return m + log2f(1.0f + exp2f(n - m));
}

// async 4B global->LDS DMA: each lane reads its own global addr g, deposits at
// ldsbase + lane*4. LDS base must be wave-uniform.
__device__ __forceinline__ void gl_lds_b32(const float* g, float* l) {
  __builtin_amdgcn_global_load_lds(
      (const __attribute__((address_space(1))) unsigned int*)g,
      (__attribute__((address_space(3))) unsigned int*)l, 4, 0, 0);
}

// ============================================================================
// Kernel 1: per (t,b) row: logsumexp over V, emit LOG2-softmax probs,
// transposed layout lp[b][c][t], c=0 blank, c=1..L labels, stride Tp floats.
// ============================================================================
__global__ __launch_bounds__(256) void k_prob_gather(
    const float* __restrict__ acts, const int* __restrict__ labels,
    float* __restrict__ lp, int T, int Tp, int B, int V, int L) {
  const int lane = threadIdx.x & 63;
  const uint32_t r = blockIdx.x * 4u + (threadIdx.x >> 6);
  if (r >= (uint32_t)(T * B)) return;
  const uint32_t b = r / (uint32_t)T;
  const uint32_t t = r % (uint32_t)T;
  const float* __restrict__ row = acts + ((size_t)t * (size_t)B + b) * (size_t)V;

  float mx, l2s;
  if (V == 2048) {
    const float4* row4 = (const float4*)row;
    float vals[32];
    mx = -3.0e38f;
#pragma unroll
    for (int q = 0; q < 8; ++q) {
      float4 v = row4[lane + (q << 6)];
      vals[q*4+0] = v.x; vals[q*4+1] = v.y; vals[q*4+2] = v.z; vals[q*4+3] = v.w;
      mx = fmaxf(mx, fmaxf(fmaxf(v.x, v.y), fmaxf(v.z, v.w)));
    }
#pragma unroll
    for (int off = 32; off >= 1; off >>= 1) mx = fmaxf(mx, __shfl_xor(mx, off, 64));
    float s = 0.0f;
#pragma unroll
    for (int k = 0; k < 32; ++k) s += exp2f((vals[k] - mx) * LOG2E);
#pragma unroll
    for (int off = 32; off >= 1; off >>= 1) s += __shfl_xor(s, off, 64);
    l2s = log2f(s);
  } else {
    float m = -3.0e38f, s = 0.0f;
    for (int i = lane; i < V; i += 64) {
      float x = row[i];
      float m2 = fmaxf(m, x);
      s = s * exp2f((m - m2) * LOG2E) + exp2f((x - m2) * LOG2E);
      m = m2;
    }
#pragma unroll
    for (int off = 32; off >= 1; off >>= 1) {
      float mo = __shfl_xor(m, off, 64), so = __shfl_xor(s, off, 64);
      float m2 = fmaxf(m, mo);
      s = s * exp2f((m - m2) * LOG2E) + so * exp2f((mo - m2) * LOG2E);
      m = m2;
    }
    mx = m;
    l2s = log2f(s);
  }

  float* __restrict__ out = lp + (size_t)b * (size_t)(L + 1) * (size_t)Tp;
  if (lane < L) {
    int lab = labels[b * (uint32_t)L + lane];
    out[(size_t)(1 + lane) * Tp + t] = (row[lab] - mx) * LOG2E - l2s;
  }
  if (lane == 0) out[t] = (row[0] - mx) * LOG2E - l2s;
}

// ============================================================================
// Kernel 2: CTC forward recurrence, LOG2 domain, one wave per batch element.
// Lane i owns states s0=2i (blank), s1=2i+1 (label i); s2 duplicates state
// 2i+2 (lane 63's s2 = terminal blank 2L). Single DPP per step.
// Staging: global->LDS DMA ring (4 windows x 8 steps), spill-proof —
// rounds 4-6 proved register windows get parked in scratch regardless of asm
// pinning (VGPR_Count 44 < 64 required). 9 x 4B DMA per window, manual
// s_waitcnt vmcnt(27) gates consumption; ds_read scheduling left to compiler.
// ============================================================================
__global__ __launch_bounds__(64, 1) void k_ctc_fwd(
    const float* __restrict__ lp, const int* __restrict__ labels,
    const int* __restrict__ act_lens, const int* __restrict__ label_lens,
    float* __restrict__ loss, int T, int Tp, int B, int L) {
  const int b = blockIdx.x;
  const int lane = threadIdx.x;
  const int Tact = __builtin_amdgcn_readfirstlane(min(act_lens[b], T));
  const int ll   = __builtin_amdgcn_readfirstlane(min(label_lens[b], L));

  const float* __restrict__ chb = lp + (size_t)b * (size_t)(L + 1) * (size_t)Tp;
  const int lclamp = (lane < L) ? lane : (L - 1);
  const float* __restrict__ chl = chb + (size_t)(1 + lclamp) * (size_t)Tp;

  int lab_i = (lane < L) ? labels[(size_t)b * L + lane] : 0;
  int lab_p = (lane >= 1 && lane - 1 < L) ? labels[(size_t)b * L + lane - 1] : -1;
  const bool allow2 = (lane >= 1) && (lab_i != 0) && (lab_i != lab_p);

  __shared__ float ringL[4][8][64];   // [window][step][lane] label log2-probs
  __shared__ float ringB[4][64];      // [window][lane&7]     blank log2-probs

  // drain any prologue loads so vmcnt bookkeeping is exact
  asm volatile("s_waitcnt vmcnt(0) lgkmcnt(0)" ::: "memory");
  __builtin_amdgcn_sched_barrier(0);

  // 9 async DMAs per window: 8 label rows (per-lane channel) + 1 blank row
#define LOADW(s, tt) { int tc = (tt); if (tc > Tp - 8) tc = Tp - 8;          \
    gl_lds_b32(chb + tc + (lane & 7), &ringB[s][0]);                         \
    gl_lds_b32(chl + tc + 0, &ringL[s][0][0]);                               \
    gl_lds_b32(chl + tc + 1, &ringL[s][1][0]);                               \
    gl_lds_b32(chl + tc + 2, &ringL[s][2][0]);                               \
    gl_lds_b32(chl + tc + 3, &ringL[s][3][0]);                               \
    gl_lds_b32(chl + tc + 4, &ringL[s][4][0]);                               \
    gl_lds_b32(chl + tc + 5, &ringL[s][5][0]);                               \
    gl_lds_b32(chl + tc + 6, &ringL[s][6][0]);                               \
    gl_lds_b32(chl + tc + 7, &ringL[s][7][0]); }

  // compiler memory barrier: following ds_reads cannot hoist above the wait
#define WAITV(N) asm volatile("s_waitcnt vmcnt(" #N ")" ::: "memory");

  // log2-domain step, data from LDS ring
#define ST(s, k) { float lpb = ringB[s][k]; float lpl = ringL[s][k][lane];   \
    float pa = dpp_shr1(s1);                                                 \
    float c2 = allow2 ? pa : NEGF;                                           \
    float m0 = fmaxf(s0, pa), n0 = fminf(s0, pa);                            \
    float ns0 = (m0 + lpb) + log2f(1.0f + exp2f(n0 - m0));                   \
    float m1 = fmaxf(fmaxf(s1, s0), c2);                                     \
    float sS = exp2f(s1 - m1) + exp2f(s0 - m1) + exp2f(c2 - m1);             \
    float ns1 = (m1 + lpl) + log2f(sS);                                      \
    float m2 = fmaxf(s2, s1), n2 = fminf(s2, s1);                            \
    float ns2 = (m2 + lpb) + log2f(1.0f + exp2f(n2 - m2));                   \
    s0 = ns0; s1 = ns1; s2 = ns2; }

#define PROCF(s) { ST(s,0) ST(s,1) ST(s,2) ST(s,3)                           \
                   ST(s,4) ST(s,5) ST(s,6) ST(s,7) }

#define STG(s, k, tt) { if ((tt) >= 1 && (tt) < Tact) ST(s, k) }

#define PROCG(s, tb) { STG(s,0,(tb)+0) STG(s,1,(tb)+1) STG(s,2,(tb)+2)       \
                       STG(s,3,(tb)+3) STG(s,4,(tb)+4) STG(s,5,(tb)+5)       \
                       STG(s,6,(tb)+6) STG(s,7,(tb)+7) }

  LOADW(0, 0) LOADW(1, 8) LOADW(2, 16) LOADW(3, 24)
  WAITV(27)   // window 0 (oldest 9 of 36) complete

  // t=0 init: alpha[0]=lp_blank(0) at lane0.s0, alpha[1]=lp_label0(0) at lane0.s1
  float blk0 = ringB[0][0];
  float lbl0 = ringL[0][0][lane];
  float s0 = (lane == 0) ? blk0 : NEGF;
  float s1 = (lane == 0) ? lbl0 : NEGF;
  float s2 = NEGF;

  PROCG(0, 0)            // steps 1..7 (t=0 skipped by guard)
  LOADW(0, 32)
  int t0 = 8;
  for (;;) {
    if (t0 + 8 > Tact) break;
    WAITV(27) PROCF(1) LOADW(1, t0 + 32) t0 += 8;
    if (t0 + 8 > Tact) break;
    WAITV(27) PROCF(2) LOADW(2, t0 + 32) t0 += 8;
    if (t0 + 8 > Tact) break;
    WAITV(27) PROCF(3) LOADW(3, t0 + 32) t0 += 8;
    if (t0 + 8 > Tact) break;
    WAITV(27) PROCF(0) LOADW(0, t0 + 32) t0 += 8;
  }
  if (t0 < Tact) {
    WAITV(0)            // drain all in-flight DMAs (avoid LDS write race)
    LOADW(0, t0)
    WAITV(0)
    PROCG(0, t0)
  }

#undef LOADW
#undef WAITV
#undef ST
#undef PROCF
#undef STG
#undef PROCG

  __shared__ float A_[132];
  A_[2 * lane] = s0;
  A_[2 * lane + 1] = s1;
  if (lane == 63) A_[128] = s2;
  __syncthreads();
  if (lane == 0) {
    int sl = 2 * ll;
    float a1 = A_[sl];
    float a2 = (sl >= 1) ? A_[sl - 1] : NEGF;
    loss[b] = -ladd2(a1, a2) * LN2;   // log2 -> natural log
  }
}

// ============================================================================
// Kernel 3: sum per-batch losses -> d_out[0]
// ============================================================================
__global__ __launch_bounds__(64, 1) void k_sum(const float* __restrict__ loss,
                                               float* __restrict__ out, int B) {
  int lane = threadIdx.x;
  float s = 0.0f;
  for (int i = lane; i < B; i += 64) s += loss[i];
#pragma unroll
  for (int off = 32; off >= 1; off >>= 1) s += __shfl_xor(s, off, 64);
  if (lane == 0) out[0] = s;
}

extern "C" void kernel_launch(void* const* d_in, const int* in_sizes, int n_in,
                              void* d_out, int out_size, void* d_ws, size_t ws_size,
                              hipStream_t stream) {
  const float* acts       = (const float*)d_in[0];
  const int*   labels     = (const int*)d_in[1];
  const int*   act_lens   = (const int*)d_in[2];
  const int*   label_lens = (const int*)d_in[3];

  const int B = in_sizes[2];
  const int L = in_sizes[1] / B;
  const int T = 1000;   // per reference setup_inputs
  const int V = (int)((long long)in_sizes[0] / ((long long)T * (long long)B));
  const int Tp = (T + 31) & ~31;   // padded channel stride (1024 for T=1000)

  float* lp    = (float*)d_ws;                              // B*(L+1)*Tp floats
  float* lossb = lp + (size_t)B * (size_t)(L + 1) * (size_t)Tp;

  k_prob_gather<<<dim3((T * B + 3) / 4), dim3(256), 0, stream>>>(
      acts, labels, lp, T, Tp, B, V, L);
  k_ctc_fwd<<<dim3(B), dim3(64), 0, stream>>>(lp, labels, act_lens, label_lens,
                                              lossb, T, Tp, B, L);
  k_sum<<<dim3(1), dim3(64), 0, stream>>>(lossb, (float*)d_out, B);
}

// Round 8
// 230.315 us; speedup vs baseline: 1.0783x; 1.0783x over previous
//
#include <hip/hip_runtime.h>
#include <stdint.h>

#define NEGF   (-1.0e30f)
#define LOG2E  1.4426950408889634f
#define LN2    0.6931471805599453f

typedef float v4f __attribute__((ext_vector_type(4)));

// lane i <- lane i-1 (wave_shr:1 = 0x138), lane 0 <- NEGF (old value, bound_ctrl=false)
__device__ __forceinline__ float dpp_shr1(float x) {
  int r = __builtin_amdgcn_update_dpp(__float_as_int(NEGF), __float_as_int(x),
                                      0x138, 0xf, 0xf, false);
  return __int_as_float(r);
}

__device__ __forceinline__ float ladd2(float a, float b) {
  float m = fmaxf(a, b);
  float n = fminf(a, b);
  return m + log2f(1.0f + exp2f(n - m));
}

// ============================================================================
// Kernel 1: per (t,b) row: logsumexp over V, emit LOG2-softmax probs,
// transposed layout lp[b][c][t], c=0 blank, c=1..L labels, stride Tp floats.
// ============================================================================
__global__ __launch_bounds__(256) void k_prob_gather(
    const float* __restrict__ acts, const int* __restrict__ labels,
    float* __restrict__ lp, int T, int Tp, int B, int V, int L) {
  const int lane = threadIdx.x & 63;
  const uint32_t r = blockIdx.x * 4u + (threadIdx.x >> 6);
  if (r >= (uint32_t)(T * B)) return;
  const uint32_t b = r / (uint32_t)T;
  const uint32_t t = r % (uint32_t)T;
  const float* __restrict__ row = acts + ((size_t)t * (size_t)B + b) * (size_t)V;

  float mx, l2s;
  if (V == 2048) {
    const float4* row4 = (const float4*)row;
    float vals[32];
    mx = -3.0e38f;
#pragma unroll
    for (int q = 0; q < 8; ++q) {
      float4 v = row4[lane + (q << 6)];
      vals[q*4+0] = v.x; vals[q*4+1] = v.y; vals[q*4+2] = v.z; vals[q*4+3] = v.w;
      mx = fmaxf(mx, fmaxf(fmaxf(v.x, v.y), fmaxf(v.z, v.w)));
    }
#pragma unroll
    for (int off = 32; off >= 1; off >>= 1) mx = fmaxf(mx, __shfl_xor(mx, off, 64));
    float s = 0.0f;
#pragma unroll
    for (int k = 0; k < 32; ++k) s += exp2f((vals[k] - mx) * LOG2E);
#pragma unroll
    for (int off = 32; off >= 1; off >>= 1) s += __shfl_xor(s, off, 64);
    l2s = log2f(s);
  } else {
    float m = -3.0e38f, s = 0.0f;
    for (int i = lane; i < V; i += 64) {
      float x = row[i];
      float m2 = fmaxf(m, x);
      s = s * exp2f((m - m2) * LOG2E) + exp2f((x - m2) * LOG2E);
      m = m2;
    }
#pragma unroll
    for (int off = 32; off >= 1; off >>= 1) {
      float mo = __shfl_xor(m, off, 64), so = __shfl_xor(s, off, 64);
      float m2 = fmaxf(m, mo);
      s = s * exp2f((m - m2) * LOG2E) + so * exp2f((mo - m2) * LOG2E);
      m = m2;
    }
    mx = m;
    l2s = log2f(s);
  }

  float* __restrict__ out = lp + (size_t)b * (size_t)(L + 1) * (size_t)Tp;
  if (lane < L) {
    int lab = labels[b * (uint32_t)L + lane];
    out[(size_t)(1 + lane) * Tp + t] = (row[lab] - mx) * LOG2E - l2s;
  }
  if (lane == 0) out[t] = (row[0] - mx) * LOG2E - l2s;
}

// ============================================================================
// Kernel 2: CTC forward recurrence, LOG2 domain, one wave per batch element.
// Lane i owns states s0=2i (blank), s1=2i+1 (label i); s2 duplicates state
// 2i+2 (lane 63's s2 = terminal blank 2L). Single DPP per step.
// Staging v3: 16-step windows. 4 asm global_load_dwordx4 (16 VGPR only —
// un-spillable, un-sinkable) issued one window ahead; on window entry a
// data-dependent vmcnt(0) gates 16 ds_write_b32 into a pad-17 LDS tile;
// the 16-step compute reads S[lane][k] with NO asm fences inside, so the
// compiler batches the ds_reads (rounds 4-7 showed per-step data must be
// register/LDS-batched — scratch reloads and fenced per-step ds_reads both
// cost ~325 cyc/step).
// ============================================================================
__global__ __launch_bounds__(64, 4) void k_ctc_fwd(
    const float* __restrict__ lp, const int* __restrict__ labels,
    const int* __restrict__ act_lens, const int* __restrict__ label_lens,
    float* __restrict__ loss, int T, int Tp, int B, int L) {
  const int b = blockIdx.x;
  const int lane = threadIdx.x;
  const int Tact = __builtin_amdgcn_readfirstlane(min(act_lens[b], T));
  const int ll   = __builtin_amdgcn_readfirstlane(min(label_lens[b], L));

  const float* __restrict__ chb = lp + (size_t)b * (size_t)(L + 1) * (size_t)Tp;
  const int lclamp = (lane < L) ? lane : (L - 1);
  const float* __restrict__ chl = chb + (size_t)(1 + lclamp) * (size_t)Tp;

  int lab_i = (lane < L) ? labels[(size_t)b * L + lane] : 0;
  int lab_p = (lane >= 1 && lane - 1 < L) ? labels[(size_t)b * L + lane - 1] : -1;
  const bool allow2 = (lane >= 1) && (lab_i != 0) && (lab_i != lab_p);

  __shared__ float S[64][17];   // pad 17: banks (17*lane+k)%32, worst 2-way (free)
  __shared__ float A_[132];

  v4f r0, r1, r2, r3;

  // 4 x 16B loads of this lane's label channel, window [tt, tt+16)
#define LOADR(tt) { const float* p_ = chl + (tt);                            \
    asm volatile("global_load_dwordx4 %0, %4, off\n\t"                       \
                 "global_load_dwordx4 %1, %4, off offset:16\n\t"             \
                 "global_load_dwordx4 %2, %4, off offset:32\n\t"             \
                 "global_load_dwordx4 %3, %4, off offset:48"                 \
                 : "=&v"(r0), "=&v"(r1), "=&v"(r2), "=&v"(r3) : "v"(p_)); }

  // data-dependent wait: anything using r0..r3 cannot move above this
#define WAITR asm volatile("s_waitcnt vmcnt(0)"                              \
                 : "+v"(r0), "+v"(r1), "+v"(r2), "+v"(r3));

#define WRITES { S[lane][0]=r0.x;  S[lane][1]=r0.y;  S[lane][2]=r0.z;  S[lane][3]=r0.w;  \
                 S[lane][4]=r1.x;  S[lane][5]=r1.y;  S[lane][6]=r1.z;  S[lane][7]=r1.w;  \
                 S[lane][8]=r2.x;  S[lane][9]=r2.y;  S[lane][10]=r2.z; S[lane][11]=r2.w; \
                 S[lane][12]=r3.x; S[lane][13]=r3.y; S[lane][14]=r3.z; S[lane][15]=r3.w; }

  // log2-domain step; PB = log2 p_blank(t), PL = log2 p_label(t)
#define ST(PB, PL) { float pa = dpp_shr1(s1);                                \
    float c2 = allow2 ? pa : NEGF;                                           \
    float m0 = fmaxf(s0, pa), n0 = fminf(s0, pa);                            \
    float ns0 = (m0 + (PB)) + log2f(1.0f + exp2f(n0 - m0));                  \
    float m1 = fmaxf(fmaxf(s1, s0), c2);                                     \
    float sS = exp2f(s1 - m1) + exp2f(s0 - m1) + exp2f(c2 - m1);             \
    float ns1 = (m1 + (PL)) + log2f(sS);                                     \
    float m2 = fmaxf(s2, s1), n2 = fminf(s2, s1);                            \
    float ns2 = (m2 + (PB)) + log2f(1.0f + exp2f(n2 - m2));                  \
    s0 = ns0; s1 = ns1; s2 = ns2; }

#define STEPK(k, cb)  { float lpl = S[lane][k]; float lpb = (cb)[k]; ST(lpb, lpl) }
#define STEPG(k, cb, tt) { if ((tt) >= 1 && (tt) < Tact) STEPK(k, cb) }

#define WIN16(cb) { STEPK(0,cb)  STEPK(1,cb)  STEPK(2,cb)  STEPK(3,cb)       \
                    STEPK(4,cb)  STEPK(5,cb)  STEPK(6,cb)  STEPK(7,cb)       \
                    STEPK(8,cb)  STEPK(9,cb)  STEPK(10,cb) STEPK(11,cb)      \
                    STEPK(12,cb) STEPK(13,cb) STEPK(14,cb) STEPK(15,cb) }

#define WIN16G(cb, tb) { STEPG(0,cb,(tb)+0)  STEPG(1,cb,(tb)+1)  STEPG(2,cb,(tb)+2)   \
                         STEPG(3,cb,(tb)+3)  STEPG(4,cb,(tb)+4)  STEPG(5,cb,(tb)+5)   \
                         STEPG(6,cb,(tb)+6)  STEPG(7,cb,(tb)+7)  STEPG(8,cb,(tb)+8)   \
                         STEPG(9,cb,(tb)+9)  STEPG(10,cb,(tb)+10) STEPG(11,cb,(tb)+11) \
                         STEPG(12,cb,(tb)+12) STEPG(13,cb,(tb)+13) STEPG(14,cb,(tb)+14) \
                         STEPG(15,cb,(tb)+15) }

  // ---- prologue: window 0 ----
  LOADR(0)
  WAITR
  WRITES
  LOADR(16)                         // prefetch window 1 (held across compute)

  float blk0 = chb[0];
  float lbl0 = S[lane][0];
  float s0 = (lane == 0) ? blk0 : NEGF;
  float s1 = (lane == 0) ? lbl0 : NEGF;
  float s2 = NEGF;

  { const float* cb = chb; WIN16G(cb, 0) }   // steps t=1..15 (t=0 skipped)

  // ---- main loop: full 16-step windows ----
  int t0 = 16;
  while (t0 + 16 <= Tact) {
    WAITR
    WRITES
    { int tn = t0 + 16; if (tn > Tp - 16) tn = Tp - 16; LOADR(tn) }
    const float* cb = chb + t0;
    WIN16(cb)
    t0 += 16;
  }

  // ---- tail: regs hold window t0 ----
  if (t0 < Tact) {
    WAITR
    WRITES
    const float* cb = chb + t0;
    WIN16G(cb, t0)
  }

#undef LOADR
#undef WAITR
#undef WRITES
#undef ST
#undef STEPK
#undef STEPG
#undef WIN16
#undef WIN16G

  A_[2 * lane] = s0;
  A_[2 * lane + 1] = s1;
  if (lane == 63) A_[128] = s2;
  __syncthreads();
  if (lane == 0) {
    int sl = 2 * ll;
    float a1 = A_[sl];
    float a2 = (sl >= 1) ? A_[sl - 1] : NEGF;
    loss[b] = -ladd2(a1, a2) * LN2;   // log2 -> natural log
  }
}

// ============================================================================
// Kernel 3: sum per-batch losses -> d_out[0]
// ============================================================================
__global__ __launch_bounds__(64) void k_sum(const float* __restrict__ loss,
                                            float* __restrict__ out, int B) {
  int lane = threadIdx.x;
  float s = 0.0f;
  for (int i = lane; i < B; i += 64) s += loss[i];
#pragma unroll
  for (int off = 32; off >= 1; off >>= 1) s += __shfl_xor(s, off, 64);
  if (lane == 0) out[0] = s;
}

extern "C" void kernel_launch(void* const* d_in, const int* in_sizes, int n_in,
                              void* d_out, int out_size, void* d_ws, size_t ws_size,
                              hipStream_t stream) {
  const float* acts       = (const float*)d_in[0];
  const int*   labels     = (const int*)d_in[1];
  const int*   act_lens   = (const int*)d_in[2];
  const int*   label_lens = (const int*)d_in[3];

  const int B = in_sizes[2];
  const int L = in_sizes[1] / B;
  const int T = 1000;   // per reference setup_inputs
  const int V = (int)((long long)in_sizes[0] / ((long long)T * (long long)B));
  const int Tp = (T + 31) & ~31;   // padded channel stride (1024 for T=1000)

  float* lp    = (float*)d_ws;                              // B*(L+1)*Tp floats
  float* lossb = lp + (size_t)B * (size_t)(L + 1) * (size_t)Tp;

  k_prob_gather<<<dim3((T * B + 3) / 4), dim3(256), 0, stream>>>(
      acts, labels, lp, T, Tp, B, V, L);
  k_ctc_fwd<<<dim3(B), dim3(64), 0, stream>>>(lp, labels, act_lens, label_lens,
                                              lossb, T, Tp, B, L);
  k_sum<<<dim3(1), dim3(64), 0, stream>>>(lossb, (float*)d_out, B);
}

// Round 9
// 137.497 us; speedup vs baseline: 1.8063x; 1.6751x over previous
//
#include <hip/hip_runtime.h>
#include <stdint.h>

#define LOG2E  1.4426950408889634f
#define LN2    0.6931471805599453f

typedef float v4f __attribute__((ext_vector_type(4)));

// lane i <- lane i-1 (wave_shr:1 = 0x138), lane 0 <- 0.0f (bound_ctrl=true)
__device__ __forceinline__ float dpp_shr1_z(float x) {
  int r = __builtin_amdgcn_update_dpp(0, __float_as_int(x), 0x138, 0xf, 0xf, true);
  return __int_as_float(r);
}

template <int CTRL>
__device__ __forceinline__ float dpp_max(float v) {
  int r = __builtin_amdgcn_update_dpp(0, __float_as_int(v), CTRL, 0xf, 0xf, true);
  return fmaxf(v, __int_as_float(r));
}

// canonical GCN wave64 max reduce -> uniform value (via lane 63 readlane).
// alpha >= 0 so 0-fill is the identity.
__device__ __forceinline__ float wave_max_uniform(float v) {
  v = dpp_max<0x111>(v);   // row_shr:1
  v = dpp_max<0x112>(v);   // row_shr:2
  v = dpp_max<0x114>(v);   // row_shr:4
  v = dpp_max<0x118>(v);   // row_shr:8  -> lane15/31/47/63 hold row max
  v = dpp_max<0x142>(v);   // row_bcast15
  v = dpp_max<0x143>(v);   // row_bcast31 -> lane 63 = global max
  int gm = __builtin_amdgcn_readlane(__float_as_int(v), 63);
  return __int_as_float(gm);
}

// ============================================================================
// Kernel 1: per (t,b) row: softmax over V, emit LINEAR probs, transposed
// layout lp[b][c][t], c=0 blank, c=1..L labels, channel stride Tp floats.
// ============================================================================
__global__ __launch_bounds__(256) void k_prob_gather(
    const float* __restrict__ acts, const int* __restrict__ labels,
    float* __restrict__ lp, int T, int Tp, int B, int V, int L) {
  const int lane = threadIdx.x & 63;
  const uint32_t r = blockIdx.x * 4u + (threadIdx.x >> 6);
  if (r >= (uint32_t)(T * B)) return;
  const uint32_t b = r / (uint32_t)T;
  const uint32_t t = r % (uint32_t)T;
  const float* __restrict__ row = acts + ((size_t)t * (size_t)B + b) * (size_t)V;

  float mx, l2s;
  if (V == 2048) {
    const float4* row4 = (const float4*)row;
    float vals[32];
    mx = -3.0e38f;
#pragma unroll
    for (int q = 0; q < 8; ++q) {
      float4 v = row4[lane + (q << 6)];
      vals[q*4+0] = v.x; vals[q*4+1] = v.y; vals[q*4+2] = v.z; vals[q*4+3] = v.w;
      mx = fmaxf(mx, fmaxf(fmaxf(v.x, v.y), fmaxf(v.z, v.w)));
    }
#pragma unroll
    for (int off = 32; off >= 1; off >>= 1) mx = fmaxf(mx, __shfl_xor(mx, off, 64));
    float s = 0.0f;
#pragma unroll
    for (int k = 0; k < 32; ++k) s += exp2f((vals[k] - mx) * LOG2E);
#pragma unroll
    for (int off = 32; off >= 1; off >>= 1) s += __shfl_xor(s, off, 64);
    l2s = log2f(s);
  } else {
    float m = -3.0e38f, s = 0.0f;
    for (int i = lane; i < V; i += 64) {
      float x = row[i];
      float m2 = fmaxf(m, x);
      s = s * exp2f((m - m2) * LOG2E) + exp2f((x - m2) * LOG2E);
      m = m2;
    }
#pragma unroll
    for (int off = 32; off >= 1; off >>= 1) {
      float mo = __shfl_xor(m, off, 64), so = __shfl_xor(s, off, 64);
      float m2 = fmaxf(m, mo);
      s = s * exp2f((m - m2) * LOG2E) + so * exp2f((mo - m2) * LOG2E);
      m = m2;
    }
    mx = m;
    l2s = log2f(s);
  }

  float* __restrict__ out = lp + (size_t)b * (size_t)(L + 1) * (size_t)Tp;
  if (lane < L) {
    int lab = labels[b * (uint32_t)L + lane];
    out[(size_t)(1 + lane) * Tp + t] = exp2f((row[lab] - mx) * LOG2E - l2s);
  }
  if (lane == 0) out[t] = exp2f((row[0] - mx) * LOG2E - l2s);
}

// ============================================================================
// Kernel 2: CTC forward recurrence, LINEAR domain + exact power-of-2 rescale
// every 4 steps (W=4: worst-case window decay 2^-84 >> FTZ floor 2^-126;
// round 3's W=8 crossed it). One wave per batch element. Lane i owns states
// s0=2i (blank), s1=2i+1 (label i); s2 duplicates 2i+2 (lane 63: 2L).
// Single DPP per step, zero transcendentals (rounds 4-8 proved the
// exp2/log2 chain was the 400-cyc/step floor; staging is NOT the stall).
// Staging identical to round 8 (proven correct).
// ============================================================================
__global__ __launch_bounds__(64, 4) void k_ctc_fwd(
    const float* __restrict__ lp, const int* __restrict__ labels,
    const int* __restrict__ act_lens, const int* __restrict__ label_lens,
    float* __restrict__ loss, int T, int Tp, int B, int L) {
  const int b = blockIdx.x;
  const int lane = threadIdx.x;
  const int Tact = __builtin_amdgcn_readfirstlane(min(act_lens[b], T));
  const int ll   = __builtin_amdgcn_readfirstlane(min(label_lens[b], L));

  const float* __restrict__ chb = lp + (size_t)b * (size_t)(L + 1) * (size_t)Tp;
  const int lclamp = (lane < L) ? lane : (L - 1);
  const float* __restrict__ chl = chb + (size_t)(1 + lclamp) * (size_t)Tp;

  int lab_i = (lane < L) ? labels[(size_t)b * L + lane] : 0;
  int lab_p = (lane >= 1 && lane - 1 < L) ? labels[(size_t)b * L + lane - 1] : -1;
  const bool allow2 = (lane >= 1) && (lab_i != 0) && (lab_i != lab_p);

  __shared__ float S[64][17];
  __shared__ float A_[132];

  v4f r0, r1, r2, r3;
  int acc_e = 0;

#define LOADR(tt) { const float* p_ = chl + (tt);                            \
    asm volatile("global_load_dwordx4 %0, %4, off\n\t"                       \
                 "global_load_dwordx4 %1, %4, off offset:16\n\t"             \
                 "global_load_dwordx4 %2, %4, off offset:32\n\t"             \
                 "global_load_dwordx4 %3, %4, off offset:48"                 \
                 : "=&v"(r0), "=&v"(r1), "=&v"(r2), "=&v"(r3) : "v"(p_)); }

#define WAITR asm volatile("s_waitcnt vmcnt(0)"                              \
                 : "+v"(r0), "+v"(r1), "+v"(r2), "+v"(r3));

#define WRITES { S[lane][0]=r0.x;  S[lane][1]=r0.y;  S[lane][2]=r0.z;  S[lane][3]=r0.w;  \
                 S[lane][4]=r1.x;  S[lane][5]=r1.y;  S[lane][6]=r1.z;  S[lane][7]=r1.w;  \
                 S[lane][8]=r2.x;  S[lane][9]=r2.y;  S[lane][10]=r2.z; S[lane][11]=r2.w; \
                 S[lane][12]=r3.x; S[lane][13]=r3.y; S[lane][14]=r3.z; S[lane][15]=r3.w; }

  // linear-domain step: ns0=(s0+pa)*pb ; ns1=((s0+c2)+s1)*pl ; ns2=(s2+s1)*pb
#define ST(PB, PL) { float pa = dpp_shr1_z(s1);                              \
    float c2 = allow2 ? pa : 0.0f;                                           \
    float n0 = (s0 + pa) * (PB);                                             \
    float n1 = ((s0 + c2) + s1) * (PL);                                      \
    float n2 = (s2 + s1) * (PB);                                             \
    s0 = n0; s1 = n1; s2 = n2; }

  // exact power-of-2 rescale; scale is wave-uniform (readlane 63 -> SGPR)
#define RESC { float gm = wave_max_uniform(fmaxf(fmaxf(s0, s1), s2));        \
    int e = ((__float_as_int(gm) >> 23) & 0xff) - 127;                       \
    acc_e += e;                                                              \
    float sc = __int_as_float((127 - e) << 23);                              \
    s0 *= sc; s1 *= sc; s2 *= sc; }

#define STEPK(k, cb)  { float lpl = S[lane][k]; float lpb = (cb)[k]; ST(lpb, lpl) }
#define STEPG(k, cb, tt) { if ((tt) >= 1 && (tt) < Tact) STEPK(k, cb) }

#define WIN16(cb) { STEPK(0,cb)  STEPK(1,cb)  STEPK(2,cb)  STEPK(3,cb)  RESC \
                    STEPK(4,cb)  STEPK(5,cb)  STEPK(6,cb)  STEPK(7,cb)  RESC \
                    STEPK(8,cb)  STEPK(9,cb)  STEPK(10,cb) STEPK(11,cb) RESC \
                    STEPK(12,cb) STEPK(13,cb) STEPK(14,cb) STEPK(15,cb) RESC }

#define WIN16G(cb, tb) { STEPG(0,cb,(tb)+0)  STEPG(1,cb,(tb)+1)  STEPG(2,cb,(tb)+2)   \
                         STEPG(3,cb,(tb)+3)  RESC                                     \
                         STEPG(4,cb,(tb)+4)  STEPG(5,cb,(tb)+5)  STEPG(6,cb,(tb)+6)   \
                         STEPG(7,cb,(tb)+7)  RESC                                     \
                         STEPG(8,cb,(tb)+8)  STEPG(9,cb,(tb)+9)  STEPG(10,cb,(tb)+10) \
                         STEPG(11,cb,(tb)+11) RESC                                    \
                         STEPG(12,cb,(tb)+12) STEPG(13,cb,(tb)+13) STEPG(14,cb,(tb)+14) \
                         STEPG(15,cb,(tb)+15) RESC }

  // ---- prologue: window 0 ----
  LOADR(0)
  WAITR
  WRITES
  LOADR(16)

  float blk0 = chb[0];
  float lbl0 = S[lane][0];
  float s0 = (lane == 0) ? blk0 : 0.0f;
  float s1 = (lane == 0) ? lbl0 : 0.0f;
  float s2 = 0.0f;

  { const float* cb = chb; WIN16G(cb, 0) }   // t=1..15 (t=0 skipped by guard)

  // ---- main loop ----
  int t0 = 16;
  while (t0 + 16 <= Tact) {
    WAITR
    WRITES
    { int tn = t0 + 16; if (tn > Tp - 16) tn = Tp - 16; LOADR(tn) }
    const float* cb = chb + t0;
    WIN16(cb)
    t0 += 16;
  }

  // ---- tail ----
  if (t0 < Tact) {
    WAITR
    WRITES
    const float* cb = chb + t0;
    WIN16G(cb, t0)
  }

#undef LOADR
#undef WAITR
#undef WRITES
#undef ST
#undef RESC
#undef STEPK
#undef STEPG
#undef WIN16
#undef WIN16G

  A_[2 * lane] = s0;
  A_[2 * lane + 1] = s1;
  if (lane == 63) A_[128] = s2;
  __syncthreads();
  if (lane == 0) {
    int sl = 2 * ll;
    float a1 = A_[sl];
    float a2 = (sl >= 1) ? A_[sl - 1] : 0.0f;
    // true alpha = stored * 2^{acc_e}
    loss[b] = -(logf(a1 + a2) + (float)acc_e * LN2);
  }
}

// ============================================================================
// Kernel 3: sum per-batch losses -> d_out[0]
// ============================================================================
__global__ __launch_bounds__(64) void k_sum(const float* __restrict__ loss,
                                            float* __restrict__ out, int B) {
  int lane = threadIdx.x;
  float s = 0.0f;
  for (int i = lane; i < B; i += 64) s += loss[i];
#pragma unroll
  for (int off = 32; off >= 1; off >>= 1) s += __shfl_xor(s, off, 64);
  if (lane == 0) out[0] = s;
}

extern "C" void kernel_launch(void* const* d_in, const int* in_sizes, int n_in,
                              void* d_out, int out_size, void* d_ws, size_t ws_size,
                              hipStream_t stream) {
  const float* acts       = (const float*)d_in[0];
  const int*   labels     = (const int*)d_in[1];
  const int*   act_lens   = (const int*)d_in[2];
  const int*   label_lens = (const int*)d_in[3];

  const int B = in_sizes[2];
  const int L = in_sizes[1] / B;
  const int T = 1000;   // per reference setup_inputs
  const int V = (int)((long long)in_sizes[0] / ((long long)T * (long long)B));
  const int Tp = (T + 31) & ~31;   // padded channel stride (1024 for T=1000)

  float* lp    = (float*)d_ws;                              // B*(L+1)*Tp floats
  float* lossb = lp + (size_t)B * (size_t)(L + 1) * (size_t)Tp;

  k_prob_gather<<<dim3((T * B + 3) / 4), dim3(256), 0, stream>>>(
      acts, labels, lp, T, Tp, B, V, L);
  k_ctc_fwd<<<dim3(B), dim3(64), 0, stream>>>(lp, labels, act_lens, label_lens,
                                              lossb, T, Tp, B, L);
  k_sum<<<dim3(1), dim3(64), 0, stream>>>(lossb, (float*)d_out, B);
}